// Round 9
// baseline (202.928 us; speedup 1.0000x reference)
//
#include <hip/hip_runtime.h>
#include <hip/hip_fp16.h>
#include <math.h>

#define NPROJ 96
#define NANG  96
#define DET   192
#define NPIX  16384            // 128*128
#define SLICE (NANG*DET)       // 18432

// DSD/DU = DSD/DV = 1000/3.5
#define KPROJ 285.7142857142857f

__device__ __forceinline__ float frcp(float x) { return __builtin_amdgcn_rcpf(x); }

__device__ __forceinline__ float ffract(float x) {
#if __has_builtin(__builtin_amdgcn_fractf)
    return __builtin_amdgcn_fractf(x);
#else
    return x - floorf(x);
#endif
}

typedef __fp16 h2 __attribute__((ext_vector_type(2)));

__device__ __forceinline__ unsigned pack2(float a, float b) {
    h2 p = __builtin_amdgcn_cvt_pkrtz(a, b);
    return __builtin_bit_cast(unsigned, p);
}
__device__ __forceinline__ h2 as_h2(unsigned u) { return __builtin_bit_cast(h2, u); }

#if __has_builtin(__builtin_amdgcn_fdot2)
#define FDOT2(a, b, c) __builtin_amdgcn_fdot2((a), (b), (c), false)
#else
__device__ __forceinline__ float FDOT2(h2 a, h2 b, float c) {
    return c + (float)a[0] * (float)b[0] + (float)a[1] * (float)b[1];
}
#endif

// ---------------------------------------------------------------------------
// K1: deriv = grad_lastdim(sino * weight) -> packed fp16 PAIRS:
// derivp[row][d] = half2(g[d], g[d+1]).
// ---------------------------------------------------------------------------
__global__ __launch_bounds__(192) void k_deriv(const float* __restrict__ sino,
                                               const float* __restrict__ wgt,
                                               unsigned* __restrict__ derivp) {
    __shared__ float row[DET];
    const int r = blockIdx.x;          // p*96 + a
    const int d = threadIdx.x;         // 0..191
    const int base = r * DET + d;
    row[d] = sino[base] * wgt[base];
    __syncthreads();
    float g0, g1;
    if (d == 0)            g0 = row[1] - row[0];
    else if (d == DET-1)   g0 = row[DET-1] - row[DET-2];
    else                   g0 = 0.5f * (row[d+1] - row[d-1]);
    if (d >= DET-2)        g1 = (d == DET-1) ? 0.0f : row[DET-1] - row[DET-2];
    else                   g1 = 0.5f * (row[d+2] - row[d]);
    derivp[base] = pack2(g0, g1);
}

// ---------------------------------------------------------------------------
// K2: 2D backprojection + cosine weighting -> packed QUAD layout for bp3d.
// Angle-pair ILP: angles a and a+48 differ by pi/2 (cos->-sin, sin->cos),
// processed together -> 4 independent load streams/iter, 48 iterations.
// grid (96 p, 32 chunks), block 256, 2 px/thread = 3072 blocks.
// pos in [5.7,185.3] -> no masks.
// ---------------------------------------------------------------------------
__global__ __launch_bounds__(256) void k_bp2d(const unsigned* __restrict__ derivp,
                                              unsigned* __restrict__ wcb4) {
    __shared__ float sc[NANG], ss[NANG];
    __shared__ float buf[512];
    const int p   = blockIdx.x;
    const int tid = threadIdx.x;

    if (tid < NANG) {
        float s_, c_;
        sincosf((float)tid * (float)(3.14159265358979323846 / 96.0), &s_, &c_);
        sc[tid] = c_; ss[tid] = s_;
    }

    const int pixbase = blockIdx.y * 512;
    float acc[2], fx[2], fy[2];
    #pragma unroll
    for (int i = 0; i < 2; ++i) {
        const int pix = pixbase + i*256 + tid;
        fx[i] = (float)(pix & 127) - 63.5f;
        fy[i] = (float)(pix >> 7)  - 63.5f;
        acc[i] = 0.0f;
    }
    __syncthreads();   // trig ready

    const unsigned* slice = derivp + p * SLICE;
    for (int a = 0; a < NANG/2; ++a) {
        const float cb = sc[a], sb = ss[a];
        const unsigned* rowA = slice + a * DET;
        const unsigned* rowB = rowA + 48 * DET;
        // positions for both angles, both pixels (4 independent streams)
        float posA[2], posB[2];
        int   iA[2], iB[2];
        #pragma unroll
        for (int i = 0; i < 2; ++i) {
            posA[i] = fmaf(cb, fx[i], fmaf( sb, fy[i], 95.5f));   // angle a
            posB[i] = fmaf(cb, fy[i], fmaf(-sb, fx[i], 95.5f));   // angle a+48
            iA[i] = (int)posA[i];  iB[i] = (int)posB[i];
        }
        unsigned gA[2], gB[2];
        #pragma unroll
        for (int i = 0; i < 2; ++i) { gA[i] = rowA[iA[i]]; gB[i] = rowB[iB[i]]; }
        #pragma unroll
        for (int i = 0; i < 2; ++i) {
            const float fA = ffract(posA[i]);
            const float fB = ffract(posB[i]);
            acc[i] = FDOT2(as_h2(gA[i]), as_h2(pack2(1.0f - fA, fA)), acc[i]);
            acc[i] = FDOT2(as_h2(gB[i]), as_h2(pack2(1.0f - fB, fB)), acc[i]);
        }
    }

    // cosine-weight, pack (u,u+1) pairs via LDS, dual-store into quad layout
    #pragma unroll
    for (int i = 0; i < 2; ++i) {
        const float w = 1000.0f * rsqrtf(1000000.0f + fx[i]*fx[i] + fy[i]*fy[i]);
        buf[i*256 + tid] = acc[i] * w;
    }
    __syncthreads();
    unsigned* slice4 = wcb4 + p * (NPIX * 2);    // uint2 viewed as 2 dwords
    #pragma unroll
    for (int i = 0; i < 2; ++i) {
        const int l   = i*256 + tid;
        const int pix = pixbase + l;
        const int u   = pix & 127;
        const int v   = pix >> 7;
        const float v0 = buf[l];
        const float v1 = (u < 127) ? buf[l + 1] : 0.0f;   // u=127 pair unused
        const unsigned pr = pack2(v0, v1);
        slice4[pix * 2] = pr;                         // wcb4[v][u].x
        if (v >= 1) slice4[(pix - 128) * 2 + 1] = pr; // wcb4[v-1][u].y
    }
}

// ---------------------------------------------------------------------------
// K3: 3D cone-beam backprojection + PReLU — barrier-free, quad-packed taps,
// beta-pair ILP: betas b and b+48 differ by pi (cos->-c, sin->-s) so
// t2=-t, s2=-s — one t/s serves both. 48 iterations, 8 independent load
// streams each. grid (64 y-pairs, 32 z-chunks) = 2048 blocks = 8/CU.
// pu in [11,116], pv in [19,108] -> no masks.
// ---------------------------------------------------------------------------
__global__ __launch_bounds__(256) void k_bp3d(const uint2* __restrict__ wcb4,
                                              const float* __restrict__ prelu,
                                              float* __restrict__ out) {
    __shared__ float sc[NPROJ], ss[NPROJ];
    const int tid = threadIdx.x;
    const int x   = tid & 127;
    const int y   = (blockIdx.x << 1) | (tid >> 7);
    const int z0  = blockIdx.y << 2;

    if (tid < NPROJ) {
        float s_, c_;
        sincosf((float)tid * (float)(2.0 * 3.14159265358979323846 / 96.0), &s_, &c_);
        sc[tid] = c_; ss[tid] = s_;
    }

    const float fx  = (float)x - 63.5f;
    const float fy  = (float)y - 63.5f;
    const float zlo = (float)z0 - 63.5f;

    float acc[4];
    #pragma unroll
    for (int j = 0; j < 4; ++j) acc[j] = 0.0f;

    __syncthreads();   // trig ready — the only barrier

    for (int b = 0; b < NPROJ/2; ++b) {
        const float cb = sc[b], sb = ss[b];
        const float t  = fmaf(fx, cb,  fy * sb);    // t(b);  t(b+48) = -t
        const float sd = fmaf(fy, cb, -fx * sb);    // s(b);  s(b+48) = -sd

        // ---- beta b ----
        const float invrA = frcp(500.0f + t);
        const float puA   = fmaf(KPROJ * sd, invrA, 63.5f);
        const int   iuA   = (int)puA;
        const float fuA   = ffract(puA);
        float w2A = 1000.0f * invrA; w2A *= w2A;
        const float KzA   = KPROJ * invrA;
        const h2    wuA   = as_h2(pack2(1.0f - fuA, fuA));
        // ---- beta b+48 ----
        const float invrB = frcp(500.0f - t);
        const float puB   = fmaf(-KPROJ * sd, invrB, 63.5f);
        const int   iuB   = (int)puB;
        const float fuB   = ffract(puB);
        float w2B = 1000.0f * invrB; w2B *= w2B;
        const float KzB   = KPROJ * invrB;
        const h2    wuB   = as_h2(pack2(1.0f - fuB, fuB));

        const uint2* bbA = wcb4 + b * NPIX;
        const uint2* bbB = bbA + 48 * NPIX;

        int   offA[4], offB[4];
        float fvA[4], fvB[4];
        #pragma unroll
        for (int j = 0; j < 4; ++j) {
            const float zj  = zlo + (float)j;
            const float pvA = fmaf(KzA, zj, 63.5f);
            const float pvB = fmaf(KzB, zj, 63.5f);
            const int   ivA = (int)pvA;
            const int   ivB = (int)pvB;
            fvA[j]  = ffract(pvA);
            fvB[j]  = ffract(pvB);
            offA[j] = (ivA << 7) + iuA;
            offB[j] = (ivB << 7) + iuB;
        }
        uint2 gA[4], gB[4];
        #pragma unroll
        for (int j = 0; j < 4; ++j) { gA[j] = bbA[offA[j]]; gB[j] = bbB[offB[j]]; }
        #pragma unroll
        for (int j = 0; j < 4; ++j) {
            const float topA = FDOT2(as_h2(gA[j].x), wuA, 0.0f);
            const float botA = FDOT2(as_h2(gA[j].y), wuA, 0.0f);
            acc[j] = fmaf(fmaf(fvA[j], botA - topA, topA), w2A, acc[j]);
            const float topB = FDOT2(as_h2(gB[j].x), wuB, 0.0f);
            const float botB = FDOT2(as_h2(gB[j].y), wuB, 0.0f);
            acc[j] = fmaf(fmaf(fvB[j], botB - topB, topB), w2B, acc[j]);
        }
    }

    const float a = prelu[0];
    #pragma unroll
    for (int j = 0; j < 4; ++j) {
        const float v = acc[j];
        out[((z0 + j) << 14) + (y << 7) + x] = (v >= 0.0f) ? v : a * v;
    }
}

// ---------------------------------------------------------------------------
extern "C" void kernel_launch(void* const* d_in, const int* in_sizes, int n_in,
                              void* d_out, int out_size, void* d_ws, size_t ws_size,
                              hipStream_t stream) {
    const float* sino  = (const float*)d_in[0];   // (1,1,96,96,192)
    const float* wgt   = (const float*)d_in[1];   // (1,96,96,192)
    const float* prelu = (const float*)d_in[2];   // (1,)
    unsigned* derivp = (unsigned*)d_ws;           // 96*96*192 packed pairs
    unsigned* wcb4   = derivp + NPROJ * SLICE;    // 96*128*128 uint2 quads
    float* out = (float*)d_out;                   // 128^3 floats

    k_deriv<<<dim3(NPROJ * NANG), dim3(192), 0, stream>>>(sino, wgt, derivp);
    k_bp2d <<<dim3(NPROJ, 32),    dim3(256), 0, stream>>>(derivp, wcb4);
    k_bp3d <<<dim3(64, 32),       dim3(256), 0, stream>>>((const uint2*)wcb4, prelu, out);
}

// Round 10
// 199.015 us; speedup vs baseline: 1.0197x; 1.0197x over previous
//
#include <hip/hip_runtime.h>
#include <hip/hip_fp16.h>
#include <math.h>

#define NPROJ 96
#define NANG  96
#define DET   192
#define NPIX  16384            // 128*128
#define SLICE (NANG*DET)       // 18432

// DSD/DU = DSD/DV = 1000/3.5
#define KPROJ 285.7142857142857f

__device__ __forceinline__ float frcp(float x) { return __builtin_amdgcn_rcpf(x); }

__device__ __forceinline__ float ffract(float x) {
#if __has_builtin(__builtin_amdgcn_fractf)
    return __builtin_amdgcn_fractf(x);
#else
    return x - floorf(x);
#endif
}

typedef __fp16 h2 __attribute__((ext_vector_type(2)));

__device__ __forceinline__ unsigned pack2(float a, float b) {
    h2 p = __builtin_amdgcn_cvt_pkrtz(a, b);
    return __builtin_bit_cast(unsigned, p);
}
__device__ __forceinline__ h2 as_h2(unsigned u) { return __builtin_bit_cast(h2, u); }

#if __has_builtin(__builtin_amdgcn_fdot2)
#define FDOT2(a, b, c) __builtin_amdgcn_fdot2((a), (b), (c), false)
#else
__device__ __forceinline__ float FDOT2(h2 a, h2 b, float c) {
    return c + (float)a[0] * (float)b[0] + (float)a[1] * (float)b[1];
}
#endif

// ---------------------------------------------------------------------------
// K1: deriv = grad_lastdim(sino * weight) -> packed fp16 PAIRS:
// derivp[row][d] = half2(g[d], g[d+1]).
// ---------------------------------------------------------------------------
__global__ __launch_bounds__(192) void k_deriv(const float* __restrict__ sino,
                                               const float* __restrict__ wgt,
                                               unsigned* __restrict__ derivp) {
    __shared__ float row[DET];
    const int r = blockIdx.x;          // p*96 + a
    const int d = threadIdx.x;         // 0..191
    const int base = r * DET + d;
    row[d] = sino[base] * wgt[base];
    __syncthreads();
    float g0, g1;
    if (d == 0)            g0 = row[1] - row[0];
    else if (d == DET-1)   g0 = row[DET-1] - row[DET-2];
    else                   g0 = 0.5f * (row[d+1] - row[d-1]);
    if (d >= DET-2)        g1 = (d == DET-1) ? 0.0f : row[DET-1] - row[DET-2];
    else                   g1 = 0.5f * (row[d+2] - row[d]);
    derivp[base] = pack2(g0, g1);
}

// ---------------------------------------------------------------------------
// K2: 2D backprojection + cosine weighting -> packed QUAD layout for bp3d:
//   wcb4[p][v][u] = uint2{ half2(w[v][u], w[v][u+1]), half2(w[v+1][u], w[v+1][u+1]) }
// (round-8 form: single angle per iter, 2 px/thread, 3072 blocks)
// pos in [5.7,185.3] -> no masks.
// ---------------------------------------------------------------------------
__global__ __launch_bounds__(256) void k_bp2d(const unsigned* __restrict__ derivp,
                                              unsigned* __restrict__ wcb4) {
    __shared__ float sc[NANG], ss[NANG];
    __shared__ float buf[512];
    const int p   = blockIdx.x;
    const int tid = threadIdx.x;

    if (tid < NANG) {
        float s_, c_;
        sincosf((float)tid * (float)(3.14159265358979323846 / 96.0), &s_, &c_);
        sc[tid] = c_; ss[tid] = s_;
    }

    const int pixbase = blockIdx.y * 512;
    float acc[2], fx[2], fy[2];
    #pragma unroll
    for (int i = 0; i < 2; ++i) {
        const int pix = pixbase + i*256 + tid;
        fx[i] = (float)(pix & 127) - 63.5f;
        fy[i] = (float)(pix >> 7)  - 63.5f;
        acc[i] = 0.0f;
    }
    __syncthreads();   // trig ready

    const unsigned* rowp = derivp + p * SLICE;   // advances by DET per angle
    for (int a = 0; a < NANG; ++a, rowp += DET) {
        const float cb = sc[a], sb = ss[a];
        #pragma unroll
        for (int i = 0; i < 2; ++i) {
            const float pos = fmaf(cb, fx[i], fmaf(sb, fy[i], 95.5f));
            const int   i0  = (int)pos;            // pos > 0 always
            const float f   = ffract(pos);
            const h2    g   = as_h2(rowp[i0]);     // (deriv[i0], deriv[i0+1])
            acc[i] = FDOT2(g, as_h2(pack2(1.0f - f, f)), acc[i]);
        }
    }

    // cosine-weight, pack (u,u+1) pairs via LDS, dual-store into quad layout
    #pragma unroll
    for (int i = 0; i < 2; ++i) {
        const float w = 1000.0f * rsqrtf(1000000.0f + fx[i]*fx[i] + fy[i]*fy[i]);
        buf[i*256 + tid] = acc[i] * w;
    }
    __syncthreads();
    unsigned* slice4 = wcb4 + p * (NPIX * 2);    // uint2 viewed as 2 dwords
    #pragma unroll
    for (int i = 0; i < 2; ++i) {
        const int l   = i*256 + tid;
        const int pix = pixbase + l;
        const int u   = pix & 127;
        const int v   = pix >> 7;
        const float v0 = buf[l];
        const float v1 = (u < 127) ? buf[l + 1] : 0.0f;   // u=127 pair unused
        const unsigned pr = pack2(v0, v1);
        slice4[pix * 2] = pr;                         // wcb4[v][u].x
        if (v >= 1) slice4[(pix - 128) * 2 + 1] = pr; // wcb4[v-1][u].y
    }
}

// ---------------------------------------------------------------------------
// K3: 3D cone-beam backprojection + PReLU — quad-packed taps, round-8 loop,
// NEW LANE MAP: each wave = 8x8 (x,y) patch (block = 2x2 waves = 16x16 tile).
// Over an 8x8 patch iu spans ~9 u-pairs (<=2 cache lines) and iv spans ~1
// row, vs ~15-20 lines for the old 64x1 map -> 4-8x less TA line work.
// grid (64 xy-tiles, 32 z-chunks) = 2048 blocks = 8 blocks/CU.
// pu in [11,116], pv in [19,108] -> no masks.
// ---------------------------------------------------------------------------
__global__ __launch_bounds__(256) void k_bp3d(const uint2* __restrict__ wcb4,
                                              const float* __restrict__ prelu,
                                              float* __restrict__ out) {
    __shared__ float sc[NPROJ], ss[NPROJ];
    const int tid = threadIdx.x;
    const int l   = tid & 63;          // lane
    const int w   = tid >> 6;          // wave 0..3
    const int x   = ((blockIdx.x & 7) << 4) + ((w & 1) << 3) + (l & 7);
    const int y   = ((blockIdx.x >> 3) << 4) + ((w >> 1) << 3) + (l >> 3);
    const int z0  = blockIdx.y << 2;

    if (tid < NPROJ) {
        float s_, c_;
        sincosf((float)tid * (float)(2.0 * 3.14159265358979323846 / 96.0), &s_, &c_);
        sc[tid] = c_; ss[tid] = s_;
    }

    const float fx  = (float)x - 63.5f;
    const float fy  = (float)y - 63.5f;
    const float zlo = (float)z0 - 63.5f;

    float acc[4];
    #pragma unroll
    for (int j = 0; j < 4; ++j) acc[j] = 0.0f;

    __syncthreads();   // trig ready — the only barrier

    const uint2* bb = wcb4;              // uniform per-beta base (SGPR)
    for (int b = 0; b < NPROJ; ++b, bb += NPIX) {
        const float cb    = sc[b], sb = ss[b];
        const float t     = fmaf(fx, cb,  fy * sb);
        const float sdist = fmaf(fy, cb, -fx * sb);
        const float invr  = frcp(500.0f + t);
        const float pu    = fmaf(KPROJ * sdist, invr, 63.5f);
        const int   iu0   = (int)pu;             // pu in [11, 116]
        const float fu    = ffract(pu);
        float w2 = 1000.0f * invr; w2 *= w2;
        const float Kz    = KPROJ * invr;
        const h2    wu    = as_h2(pack2(1.0f - fu, fu));   // z-invariant

        int   off[4];
        float fv[4];
        #pragma unroll
        for (int j = 0; j < 4; ++j) {
            const float pv  = fmaf(Kz, zlo + (float)j, 63.5f);
            const int   iv0 = (int)pv;           // pv in [19, 108]
            fv[j]  = ffract(pv);
            off[j] = (iv0 << 7) + iu0;           // uint2-element offset
        }
        uint2 g[4];
        #pragma unroll
        for (int j = 0; j < 4; ++j) g[j] = bb[off[j]];   // all 4 taps, 8B
        #pragma unroll
        for (int j = 0; j < 4; ++j) {
            const float top = FDOT2(as_h2(g[j].x), wu, 0.0f);
            const float bot = FDOT2(as_h2(g[j].y), wu, 0.0f);
            acc[j] = fmaf(fmaf(fv[j], bot - top, top), w2, acc[j]);
        }
    }

    const float a = prelu[0];
    #pragma unroll
    for (int j = 0; j < 4; ++j) {
        const float v = acc[j];
        out[((z0 + j) << 14) + (y << 7) + x] = (v >= 0.0f) ? v : a * v;
    }
}

// ---------------------------------------------------------------------------
extern "C" void kernel_launch(void* const* d_in, const int* in_sizes, int n_in,
                              void* d_out, int out_size, void* d_ws, size_t ws_size,
                              hipStream_t stream) {
    const float* sino  = (const float*)d_in[0];   // (1,1,96,96,192)
    const float* wgt   = (const float*)d_in[1];   // (1,96,96,192)
    const float* prelu = (const float*)d_in[2];   // (1,)
    unsigned* derivp = (unsigned*)d_ws;           // 96*96*192 packed pairs
    unsigned* wcb4   = derivp + NPROJ * SLICE;    // 96*128*128 uint2 quads
    float* out = (float*)d_out;                   // 128^3 floats

    k_deriv<<<dim3(NPROJ * NANG), dim3(192), 0, stream>>>(sino, wgt, derivp);
    k_bp2d <<<dim3(NPROJ, 32),    dim3(256), 0, stream>>>(derivp, wcb4);
    k_bp3d <<<dim3(64, 32),       dim3(256), 0, stream>>>((const uint2*)wcb4, prelu, out);
}